// Round 24
// baseline (183.944 us; speedup 1.0000x reference)
//
#include <hip/hip_runtime.h>

typedef __attribute__((ext_vector_type(4))) float f32x4;
typedef __attribute__((ext_vector_type(8))) short s16x8;

static __device__ __forceinline__ ushort f2b(float f) {
  union { float f; unsigned u; } v; v.f = f;
  unsigned u = v.u;
  unsigned r = (u + 0x7fffu + ((u >> 16) & 1u)) >> 16;
  return (ushort)r;
}
static __device__ __forceinline__ float b2f(ushort h) {
  union { unsigned u; float f; } v; v.u = ((unsigned)h) << 16;
  return v.f;
}
static __device__ __forceinline__ unsigned cvtpk(float a, float b) {
  unsigned r;
  asm("v_cvt_pk_bf16_f32 %0, %1, %2" : "=v"(r) : "v"(a), "v"(b));
  return r;
}
static __device__ __forceinline__ float exp2i(float x) {
  float r;
  asm("v_exp_f32 %0, %1" : "=v"(r) : "v"(x));
  return r;
}

static __device__ __forceinline__ void gload_lds16(const ushort* g, ushort* l) {
  __builtin_amdgcn_global_load_lds(
      (const __attribute__((address_space(1))) void*)g,
      (__attribute__((address_space(3))) void*)l, 16, 0, 0);
}

#define LOG2E 1.44269504f

// ---------------- fused preprocessing: cvt(7 regions, 2xILP) + wtr + bvec + spsm ----------------
struct PrepArgs {
  const float* csrc[7];
  ushort* cdst[7];
  int cn[7];
  int cpre[8];
  const float* Wq; const float* Wk; const float* Wv; ushort* wdst;
  const float* Wqp; const float* Wkp; const float* Wvp;
  const float* bq; const float* bqp; const float* bk; const float* bkp;
  const float* bv; const float* bvp; float* bout;
  const float* sp; ushort* pout;
};

__global__ __launch_bounds__(256) void prep_k(PrepArgs a) {
  __shared__ char shmem[16672];
  int b = blockIdx.x;
  int tid = threadIdx.x;

  if (b < 7168) {  // ---- cvt: 2048 elems/block, 2 float4 per thread ----
    int e = 0;
#pragma unroll
    for (int k = 1; k < 7; ++k) e += (b >= a.cpre[k]) ? 1 : 0;
    int base = (b - a.cpre[e]) * 2048 + tid * 4;
    if (base + 1024 + 4 <= a.cn[e] || base + 4 <= a.cn[e]) {
      float4 v4a = *(const float4*)(a.csrc[e] + base);
      float4 v4b = *(const float4*)(a.csrc[e] + base + 1024);
      ushort4 o4a, o4b;
      o4a.x = f2b(v4a.x); o4a.y = f2b(v4a.y); o4a.z = f2b(v4a.z); o4a.w = f2b(v4a.w);
      o4b.x = f2b(v4b.x); o4b.y = f2b(v4b.y); o4b.z = f2b(v4b.z); o4b.w = f2b(v4b.w);
      *(ushort4*)(a.cdst[e] + base) = o4a;
      *(ushort4*)(a.cdst[e] + base + 1024) = o4b;
    }
    return;
  }
  b -= 7168;
  if (b < 768) {    // ---- wtr ----
    float (*t)[65] = (float(*)[65])shmem;
    int z = b >> 8, rem = b & 255;
    const float* src = z == 0 ? a.Wq : (z == 1 ? a.Wk : a.Wv);
    float scale = z == 0 ? 0.125f * LOG2E : 1.f;
    int r0 = (rem >> 4) * 64, c0 = (rem & 15) * 64;
    int lr = tid >> 2, lc4 = (tid & 3) * 16;
#pragma unroll
    for (int j = 0; j < 4; ++j)
      *(float4*)&t[lr][lc4 + j * 4] = *(const float4*)(src + (size_t)(r0 + lr) * 1024 + c0 + lc4 + j * 4);
    __syncthreads();
    ushort tmp[16];
#pragma unroll
    for (int j = 0; j < 16; ++j) tmp[j] = f2b(t[lc4 + j][lr] * scale);
    ushort* d = a.wdst + (size_t)z * 1048576 + (size_t)(c0 + lr) * 1024 + r0 + lc4;
    *(uint4*)d = *(uint4*)tmp;
    *(uint4*)(d + 8) = *(uint4*)(tmp + 8);
    return;
  }
  b -= 768;
  if (b < 768) {    // ---- bvec ----
    int r = b * 4 + (tid >> 6);
    int lane = tid & 63;
    int z = r >> 10, rr = r & 1023;
    const float* Wp = z == 0 ? a.Wqp : (z == 1 ? a.Wkp : a.Wvp);
    const float* bi = z == 0 ? a.bq : (z == 1 ? a.bk : a.bv);
    const float* bp = z == 0 ? a.bqp : (z == 1 ? a.bkp : a.bvp);
    float s = 0.f;
#pragma unroll
    for (int t2 = 0; t2 < 4; ++t2) {
      float4 w = *(const float4*)(Wp + (size_t)rr * 1024 + lane * 16 + t2 * 4);
      float4 bb = *(const float4*)(bi + lane * 16 + t2 * 4);
      s += w.x * bb.x + w.y * bb.y + w.z * bb.z + w.w * bb.w;
    }
#pragma unroll
    for (int m = 1; m < 64; m <<= 1) s += __shfl_xor(s, m);
    if (lane == 0) a.bout[r] = (s + bp[rr]) * (z == 0 ? 0.125f * LOG2E : 1.f);
    return;
  }
  b -= 768;
  {                 // ---- spsm: 4 rows/block, bf16 LDS staging, coalesced writes ----
    const int Lc = 2048;
    ushort (*vals)[2048] = (ushort(*)[2048])shmem;
    float* invs = (float*)(shmem + 4 * 2048 * 2);
    int row0 = b * 4;
    int grp = tid >> 6;
    int lane = tid & 63;
    const float* r = a.sp + (size_t)(row0 + grp) * Lc;
    float v[32];
    float mx = -1e30f;
#pragma unroll
    for (int c = 0; c < 8; ++c) {
      float4 f = *(const float4*)(r + lane * 4 + c * 256);
      v[c * 4 + 0] = f.x; v[c * 4 + 1] = f.y; v[c * 4 + 2] = f.z; v[c * 4 + 3] = f.w;
      mx = fmaxf(mx, fmaxf(fmaxf(f.x, f.y), fmaxf(f.z, f.w)));
    }
#pragma unroll
    for (int m = 1; m < 64; m <<= 1) mx = fmaxf(mx, __shfl_xor(mx, m));
    float s = 0.f;
#pragma unroll
    for (int j = 0; j < 32; ++j) { v[j] = __expf(v[j] - mx); s += v[j]; }
#pragma unroll
    for (int m = 1; m < 64; m <<= 1) s += __shfl_xor(s, m);
    if (lane == 0) invs[grp] = 0.5f * LOG2E / s;
#pragma unroll
    for (int c = 0; c < 8; ++c) {
      ushort4 st;
      st.x = f2b(v[c * 4 + 0]); st.y = f2b(v[c * 4 + 1]);
      st.z = f2b(v[c * 4 + 2]); st.w = f2b(v[c * 4 + 3]);
      *(ushort4*)&vals[grp][lane * 4 + c * 256] = st;
    }
    __syncthreads();
    int mb = row0 >> 6, rr = row0 & 63;
    int wv = rr >> 4, rg = (rr & 15) >> 2;
    float iv0 = invs[0], iv1 = invs[1], iv2 = invs[2], iv3 = invs[3];
#pragma unroll
    for (int half = 0; half < 2; ++half) {
      int seg = tid + half * 256;
      int nb = seg >> 4, cl = seg & 15;
      ushort ov[16];
#pragma unroll
      for (int nt = 0; nt < 4; ++nt) {
        int col = nb * 64 + nt * 16 + cl;
        ov[0 * 4 + nt] = f2b(b2f(vals[0][col]) * iv0);
        ov[1 * 4 + nt] = f2b(b2f(vals[1][col]) * iv1);
        ov[2 * 4 + nt] = f2b(b2f(vals[2][col]) * iv2);
        ov[3 * 4 + nt] = f2b(b2f(vals[3][col]) * iv3);
      }
      ushort* dst = a.pout + ((size_t)(mb * 32 + nb)) * 4096 + wv * 1024 + rg * 256 + cl * 16;
      *(uint4*)dst = *(uint4*)&ov[0];
      *(uint4*)(dst + 8) = *(uint4*)&ov[8];
    }
  }
}

// ---------------- bf16 GEMM, dbuf 2-phase, T2 XOR-swizzled LDS ----------------
// ZM: 0=plain 1=z-batched 2=split-K4 3=split-K4 with fused acomb A-staging
// (A = (sum_s opart_s)/(sum_s lbuf_s), computed during reg-staged A-tile load;
// LDS layout/swizzle identical to the gload_lds path: dest lane*16B, source
// col key (lc^lr)*8). vTout (QKV gemm): V cols written transposed to vT.
template <int BM, int ZM>
__global__ __launch_bounds__(256, BM == 64 ? 3 : 2) void gemm_k(
    const ushort* __restrict__ A, const ushort* __restrict__ W,
    const float* __restrict__ bias, void* __restrict__ Cv,
    int M, int N, int K, int relu, float oscale,
    ushort* __restrict__ vTout,
    const ushort* __restrict__ opA, const float* __restrict__ lbA) {
  constexpr int MT = BM / 32;
  __shared__ ushort As0[BM][64], Bs0[128][64];
  __shared__ ushort As1[BM][64], Bs1[128][64];
  const int z = (ZM != 0) ? blockIdx.z : 0;
  if (ZM == 1) { A += (size_t)z * M * K; W += (size_t)z * N * K; }
  int kb0 = 0, kb1 = K;
  if (ZM == 2 || ZM == 3) { int kh = K >> 2; kb0 = z * kh; kb1 = kb0 + kh; }
  const int tid = threadIdx.x;
  const int lane = tid & 63;
  const int wave = tid >> 6;
  const int wm = (wave >> 1) * (BM / 2);
  const int wn = (wave & 1) * 64;
  const int bm = blockIdx.x * BM;
  const int bn = blockIdx.y * 128;
  const int cl = lane & 15, rg = lane >> 4;
  const int lrow = lane >> 3;
  const int lcol = ((lane & 7) ^ lrow) * 8;  // swizzled global source column

  f32x4 acc[MT][4];
#pragma unroll
  for (int i = 0; i < MT; ++i)
#pragma unroll
    for (int j = 0; j < 4; ++j) acc[i][j] = (f32x4){0.f, 0.f, 0.f, 0.f};

  const ushort* gA = A + (size_t)(bm + wave * 8 + lrow) * K + lcol;
  const ushort* gB = W + (size_t)(bn + wave * 8 + lrow) * K + lcol;

  auto stage = [&](ushort* lA, ushort* lB, int k0) {
    if constexpr (ZM == 3) {
      int h = k0 >> 6;  // lcol < 64, k0 multiple of 64 -> whole 16B span in one head block
#pragma unroll
      for (int c = 0; c < MT; ++c) {
        int row = bm + wave * 8 + lrow + c * 32;
        float ls = lbA[(size_t)(0 + h) * 2048 + row] +
                   lbA[(size_t)(16 + h) * 2048 + row] +
                   lbA[(size_t)(32 + h) * 2048 + row] +
                   lbA[(size_t)(48 + h) * 2048 + row];
        float inv = 1.f / ls;
        float sum8[8] = {0.f, 0.f, 0.f, 0.f, 0.f, 0.f, 0.f, 0.f};
#pragma unroll
        for (int s2 = 0; s2 < 4; ++s2) {
          const ushort* sp2 = opA + ((size_t)s2 * 2048 + row) * 1024 + k0 + lcol;
          ushort4 u0 = *(const ushort4*)sp2;
          ushort4 u1 = *(const ushort4*)(sp2 + 4);
          sum8[0] += b2f(u0.x); sum8[1] += b2f(u0.y);
          sum8[2] += b2f(u0.z); sum8[3] += b2f(u0.w);
          sum8[4] += b2f(u1.x); sum8[5] += b2f(u1.y);
          sum8[6] += b2f(u1.z); sum8[7] += b2f(u1.w);
        }
        ushort pk[8];
#pragma unroll
        for (int j = 0; j < 8; ++j) pk[j] = f2b(sum8[j] * inv);
        *(uint4*)(lA + wave * 512 + c * 2048 + lane * 8) = *(uint4*)&pk[0];
      }
    } else {
#pragma unroll
      for (int c = 0; c < MT; ++c)
        gload_lds16(gA + (size_t)(c * 32) * K + k0, lA + wave * 512 + c * 2048);
    }
#pragma unroll
    for (int c = 0; c < 4; ++c)
      gload_lds16(gB + (size_t)(c * 32) * K + k0, lB + wave * 512 + c * 2048);
  };
  auto compute = [&](const ushort* As, const ushort* Bs) {
#pragma unroll
    for (int kk = 0; kk < 64; kk += 32) {
      const int slot = (kk >> 3) + rg;  // global k-slot 0..7
      s16x8 af[MT], bf[4];
#pragma unroll
      for (int mt = 0; mt < MT; ++mt) {
        int r = wm + mt * 16 + cl;
        af[mt] = *(const s16x8*)(As + r * 64 + ((slot ^ (r & 7)) << 3));
      }
#pragma unroll
      for (int nt = 0; nt < 4; ++nt) {
        int r = wn + nt * 16 + cl;
        bf[nt] = *(const s16x8*)(Bs + r * 64 + ((slot ^ (r & 7)) << 3));
      }
#pragma unroll
      for (int mt = 0; mt < MT; ++mt)
#pragma unroll
        for (int nt = 0; nt < 4; ++nt)
          acc[mt][nt] = __builtin_amdgcn_mfma_f32_16x16x32_bf16(af[mt], bf[nt], acc[mt][nt], 0, 0, 0);
    }
  };

  const int ktiles = (kb1 - kb0) >> 6;  // all our K sizes give an even count
  stage(&As0[0][0], &Bs0[0][0], kb0);
  __syncthreads();
  for (int tt = 0; tt < ktiles; tt += 2) {
    stage(&As1[0][0], &Bs1[0][0], kb0 + (tt + 1) * 64);
    compute(&As0[0][0], &Bs0[0][0]);
    __syncthreads();
    if (tt + 2 < ktiles) stage(&As0[0][0], &Bs0[0][0], kb0 + (tt + 2) * 64);
    compute(&As1[0][0], &Bs1[0][0]);
    __syncthreads();
  }

  ushort* Cu = (ushort*)Cv;
  if (ZM != 0) Cu += (size_t)z * M * N;
#pragma unroll
  for (int nt = 0; nt < 4; ++nt) {
    int c = bn + wn + nt * 16 + cl;
    float bv = (bias && ZM < 2) ? bias[c] : 0.f;
#pragma unroll
    for (int mt = 0; mt < MT; ++mt) {
      float v0 = (acc[mt][nt][0] + bv) * oscale;
      float v1 = (acc[mt][nt][1] + bv) * oscale;
      float v2 = (acc[mt][nt][2] + bv) * oscale;
      float v3 = (acc[mt][nt][3] + bv) * oscale;
      if (relu) {
        v0 = fmaxf(v0, 0.f); v1 = fmaxf(v1, 0.f);
        v2 = fmaxf(v2, 0.f); v3 = fmaxf(v3, 0.f);
      }
      unsigned p01 = cvtpk(v0, v1), p23 = cvtpk(v2, v3);
      int r0 = bm + wm + mt * 16 + rg * 4;
      if (ZM == 0 && vTout != nullptr && c >= 2048) {
        ushort4 ov;
        ov.x = (ushort)p01; ov.y = (ushort)(p01 >> 16);
        ov.z = (ushort)p23; ov.w = (ushort)(p23 >> 16);
        *(ushort4*)(vTout + (size_t)(c - 2048) * 2048 + r0) = ov;
      } else {
        size_t b = (size_t)r0 * N + c;
        Cu[b] = (ushort)p01;
        Cu[b + N] = (ushort)(p01 >> 16);
        Cu[b + 2 * N] = (ushort)p23;
        Cu[b + 3 * N] = (ushort)(p23 >> 16);
      }
    }
  }
}

// ---------------- flash attention: QBLK=128, exp2 softmax, KV-split=4 ----------------
__global__ __launch_bounds__(256, 4) void attn_k(
    const ushort* __restrict__ qkv, const ushort* __restrict__ vT,
    const ushort* __restrict__ biasP, ushort* __restrict__ opart,
    float* __restrict__ lbuf) {
  const int Lc = 2048;
  int bid = blockIdx.x;
  int xcd = bid & 7;
  int idx = bid >> 3;            // 0..127
  int h = idx & 15;
  int combo = xcd * 8 + (idx >> 4);  // 0..63
  int m0 = (combo & 15) * 128;
  int s = combo >> 4;
  int nb = s * 512, ne = nb + 512;
  int tid = threadIdx.x, lane = tid & 63, wave = tid >> 6;

  __shared__ ushort KsL[64 * 64];
  __shared__ ushort VsL[64 * 64];
  __shared__ ushort Ps[4][2][16][72];

  const int rg = lane >> 4, cl = lane & 15;
  const int kb = 8 * rg;
  const int pskey = (cl >> 2) << 3;  // Ps read-side XOR key (row = cl)
  const int lr = lane >> 3, lc = lane & 7;
  const int ssw = (lc ^ lr) * 8;     // swizzled global source slot

  s16x8 qfr[2][2];
#pragma unroll
  for (int mh = 0; mh < 2; ++mh) {
    const ushort* qp = qkv + (size_t)(m0 + mh * 64 + wave * 16 + cl) * 3072 + h * 64;
    qfr[mh][0] = *(const s16x8*)(qp + kb);
    qfr[mh][1] = *(const s16x8*)(qp + 32 + kb);
  }

  // per-thread-contiguous bias bases: [(mb*32+nb)][wave][lane][16]
  const ushort* bpB0 = biasP + ((size_t)(m0 >> 6) * 32) * 4096 + (size_t)wave * 1024 + lane * 16;
  const ushort* bpB1 = bpB0 + (size_t)32 * 4096;

  f32x4 oacc[2][4];
#pragma unroll
  for (int mh = 0; mh < 2; ++mh)
#pragma unroll
    for (int i = 0; i < 4; ++i) oacc[mh][i] = (f32x4){0.f, 0.f, 0.f, 0.f};
  float lacc[2][4] = {{0.f, 0.f, 0.f, 0.f}, {0.f, 0.f, 0.f, 0.f}};

  const ushort* gK = qkv + 1024 + h * 64 + ssw;
  const ushort* gV = vT + (size_t)h * 64 * 2048 + ssw;

  for (int n0 = nb; n0 < ne; n0 += 64) {
    __syncthreads();
#pragma unroll
    for (int pp = 0; pp < 2; ++pp) {
      int rbase = wave * 8 + pp * 32;
      int row = rbase + lr;
      gload_lds16(gK + (size_t)(n0 + row) * 3072, &KsL[rbase * 64]);
      gload_lds16(gV + (size_t)row * 2048 + n0, &VsL[rbase * 64]);
    }
    __syncthreads();

#pragma unroll
    for (int mh = 0; mh < 2; ++mh) {
      const ushort* bp = (mh ? bpB1 : bpB0) + (size_t)(n0 >> 6) * 4096;
      uint4 bv0 = *(const uint4*)bp;
      uint4 bv1 = *(const uint4*)(bp + 8);
      ushort bvals[16];
      *(uint4*)&bvals[0] = bv0;
      *(uint4*)&bvals[8] = bv1;
      f32x4 sacc[4];
#pragma unroll
      for (int i = 0; i < 4; ++i)
#pragma unroll
        for (int nt = 0; nt < 4; ++nt)
          sacc[nt][i] = b2f(bvals[i * 4 + nt]);

      __builtin_amdgcn_s_setprio(1);
#pragma unroll
      for (int kk2 = 0; kk2 < 2; ++kk2) {
#pragma unroll
        for (int nt = 0; nt < 4; ++nt) {
          int r = nt * 16 + cl;
          s16x8 b = *(const s16x8*)&KsL[r * 64 + (((kk2 * 4 + rg) ^ (cl & 7)) << 3)];
          sacc[nt] = __builtin_amdgcn_mfma_f32_16x16x32_bf16(qfr[mh][kk2], b, sacc[nt], 0, 0, 0);
        }
      }
      __builtin_amdgcn_s_setprio(0);

#pragma unroll
      for (int i = 0; i < 4; ++i) {
#pragma unroll
        for (int nt = 0; nt < 4; ++nt) {
          float pv = exp2i(sacc[nt][i]);
          sacc[nt][i] = pv;
          lacc[mh][i] += pv;
        }
      }
      const int wkey = rg << 3;
#pragma unroll
      for (int nt = 0; nt < 4; ++nt) {
        int colb = (nt * 16 + cl) ^ wkey;
        unsigned p01 = cvtpk(sacc[nt][0], sacc[nt][1]);
        unsigned p23 = cvtpk(sacc[nt][2], sacc[nt][3]);
        Ps[wave][mh][rg * 4 + 0][colb] = (ushort)p01;
        Ps[wave][mh][rg * 4 + 1][colb] = (ushort)(p01 >> 16);
        Ps[wave][mh][rg * 4 + 2][colb] = (ushort)p23;
        Ps[wave][mh][rg * 4 + 3][colb] = (ushort)(p23 >> 16);
      }
    }

    __builtin_amdgcn_s_setprio(1);
#pragma unroll
    for (int mh = 0; mh < 2; ++mh) {
#pragma unroll
      for (int kk = 0; kk < 64; kk += 32) {
        s16x8 a = *(const s16x8*)&Ps[wave][mh][cl][(kk + kb) ^ pskey];
#pragma unroll
        for (int nt = 0; nt < 4; ++nt) {
          int r = nt * 16 + cl;
          s16x8 b = *(const s16x8*)&VsL[r * 64 + ((((kk >> 3) + rg) ^ (cl & 7)) << 3)];
          oacc[mh][nt] = __builtin_amdgcn_mfma_f32_16x16x32_bf16(a, b, oacc[mh][nt], 0, 0, 0);
        }
      }
    }
    __builtin_amdgcn_s_setprio(0);
  }

#pragma unroll
  for (int mh = 0; mh < 2; ++mh) {
#pragma unroll
    for (int nt = 0; nt < 4; ++nt) {
      unsigned p01 = cvtpk(oacc[mh][nt][0], oacc[mh][nt][1]);
      unsigned p23 = cvtpk(oacc[mh][nt][2], oacc[mh][nt][3]);
      size_t b = ((size_t)s * Lc + (m0 + mh * 64 + wave * 16 + rg * 4)) * 1024 + h * 64 + nt * 16 + cl;
      opart[b] = (ushort)p01;
      opart[b + 1024] = (ushort)(p01 >> 16);
      opart[b + 2048] = (ushort)p23;
      opart[b + 3072] = (ushort)(p23 >> 16);
    }
#pragma unroll
    for (int i = 0; i < 4; ++i) {
      float l = lacc[mh][i];
#pragma unroll
      for (int m = 1; m < 16; m <<= 1) l += __shfl_xor(l, m);
      if (cl == 0) {
        int r = m0 + mh * 64 + wave * 16 + rg * 4 + i;
        lbuf[(size_t)(s * 16 + h) * Lc + r] = l;
      }
    }
  }
}

// ---------------- fused 4-way split-K combine (bf16 partials) + residual + LayerNorm ----------------
__global__ __launch_bounds__(256) void lnf_k(const float* __restrict__ basef,
                                             const ushort* __restrict__ p,
                                             const float* __restrict__ bvec,
                                             const float* __restrict__ g,
                                             const float* __restrict__ be,
                                             int relu,
                                             ushort* __restrict__ outb,
                                             float* __restrict__ outf) {
  const int Dc = 1024;
  const size_t MN = (size_t)2048 * 1024;
  int row = blockIdx.x;
  int tid = threadIdx.x;
  int c = tid * 4;
  float4 bx = *(const float4*)(basef + (size_t)row * Dc + c);
  float4 bb = *(const float4*)(bvec + c);
  float v0 = bb.x, v1 = bb.y, v2 = bb.z, v3 = bb.w;
#pragma unroll
  for (int s = 0; s < 4; ++s) {
    ushort4 a = *(const ushort4*)(p + s * MN + (size_t)row * Dc + c);
    v0 += b2f(a.x); v1 += b2f(a.y); v2 += b2f(a.z); v3 += b2f(a.w);
  }
  if (relu) {
    v0 = fmaxf(v0, 0.f); v1 = fmaxf(v1, 0.f);
    v2 = fmaxf(v2, 0.f); v3 = fmaxf(v3, 0.f);
  }
  v0 += bx.x; v1 += bx.y; v2 += bx.z; v3 += bx.w;
  float s = v0 + v1 + v2 + v3;
  __shared__ float red[4];
#pragma unroll
  for (int m = 1; m < 64; m <<= 1) s += __shfl_xor(s, m);
  if ((tid & 63) == 0) red[tid >> 6] = s;
  __syncthreads();
  s = red[0] + red[1] + red[2] + red[3];
  float mu = s * (1.f / Dc);
  float d0 = v0 - mu, d1 = v1 - mu, d2 = v2 - mu, d3 = v3 - mu;
  float ss = d0 * d0 + d1 * d1 + d2 * d2 + d3 * d3;
  __syncthreads();
#pragma unroll
  for (int m = 1; m < 64; m <<= 1) ss += __shfl_xor(ss, m);
  if ((tid & 63) == 0) red[tid >> 6] = ss;
  __syncthreads();
  ss = red[0] + red[1] + red[2] + red[3];
  float rs = rsqrtf(ss * (1.f / Dc) + 1e-5f);
  float4 gv = *(const float4*)(g + c);
  float4 bev = *(const float4*)(be + c);
  float y0 = d0 * rs * gv.x + bev.x;
  float y1 = d1 * rs * gv.y + bev.y;
  float y2 = d2 * rs * gv.z + bev.z;
  float y3 = d3 * rs * gv.w + bev.w;
  size_t o = (size_t)row * Dc + c;
  if (outb) {
    ushort4 ob4; ob4.x = f2b(y0); ob4.y = f2b(y1); ob4.z = f2b(y2); ob4.w = f2b(y3);
    *(ushort4*)(outb + o) = ob4;
  }
  if (outf) {
    float4 of4; of4.x = y0; of4.y = y1; of4.z = y2; of4.w = y3;
    *(float4*)(outf + o) = of4;
  }
}

extern "C" void kernel_launch(void* const* d_in, const int* in_sizes, int n_in,
                              void* d_out, int out_size, void* d_ws, size_t ws_size,
                              hipStream_t stream) {
  const int L = 2048, D = 1024, H = 16, HID = 4096;
  const float* x   = (const float*)d_in[0];
  const float* sp  = (const float*)d_in[1];
  const float* Wq  = (const float*)d_in[2];  const float* bq  = (const float*)d_in[3];
  const float* Wk  = (const float*)d_in[4];  const float* bk  = (const float*)d_in[5];
  const float* Wv  = (const float*)d_in[6];  const float* bv  = (const float*)d_in[7];
  const float* Wqp = (const float*)d_in[8];  const float* bqp = (const float*)d_in[9];
  const float* Wkp = (const float*)d_in[10]; const float* bkp = (const float*)d_in[11];
  const float* Wvp = (const float*)d_in[12]; const float* bvp = (const float*)d_in[13];
  const float* Wo  = (const float*)d_in[14]; const float* bo  = (const float*)d_in[15];
  const float* W1  = (const float*)d_in[16]; const float* b1  = (const float*)d_in[17];
  const float* W2  = (const float*)d_in[18]; const float* b2  = (const float*)d_in[19];
  const float* g1  = (const float*)d_in[20]; const float* be1 = (const float*)d_in[21];
  const float* g2  = (const float*)d_in[22]; const float* be2 = (const float*)d_in[23];
  float* out = (float*)d_out;

  size_t off = 0;
  char* base = (char*)d_ws;
  auto alloc = [&](size_t b) {
    char* p = base + off;
    off += (b + 255) & ~(size_t)255;
    return p;
  };
  ushort* xb    = (ushort*)alloc((size_t)L * D * 2);
  ushort* wqpb  = (ushort*)alloc((size_t)D * D * 2);   // three contiguous (z-batch)
  ushort* wkpb  = (ushort*)alloc((size_t)D * D * 2);
  ushort* wvpb  = (ushort*)alloc((size_t)D * D * 2);
  ushort* wqTb  = (ushort*)alloc((size_t)3 * D * D * 2);
  ushort* wfused= (ushort*)alloc((size_t)3 * D * D * 2);
  ushort* qkv   = (ushort*)alloc((size_t)L * 3072 * 2);
  float*  bfused= (float*)alloc((size_t)3072 * 4);
  ushort* wob   = (ushort*)alloc((size_t)D * D * 2);
  ushort* w1b   = (ushort*)alloc((size_t)HID * D * 2);
  ushort* w2b   = (ushort*)alloc((size_t)D * HID * 2);
  ushort* spsb  = (ushort*)alloc((size_t)L * L * 2);
  ushort* opart = (ushort*)alloc((size_t)4 * L * 1024 * 2);  // attn partials
  ushort* vT    = (ushort*)alloc((size_t)H * 64 * L * 2);
  float*  lbuf  = (float*)alloc((size_t)4 * H * L * 4);
  ushort* hb    = (ushort*)alloc((size_t)L * D * 2);
  float*  hf    = (float*)alloc((size_t)L * D * 4);
  ushort* parts = (ushort*)alloc((size_t)4 * L * 1024 * 2);  // split-K partials (opart still live for Wo)

  ushort* ffn1  = wqTb;    // R1 reuse (16.8MB < 25.2MB region)

  // 1. fused preprocessing: cvt(7, 2xILP) + wtr + bvec + spsm in ONE launch
  PrepArgs pa;
  pa.csrc[0] = x;   pa.cdst[0] = xb;   pa.cn[0] = L * D;
  pa.csrc[1] = Wqp; pa.cdst[1] = wqpb; pa.cn[1] = D * D;
  pa.csrc[2] = Wkp; pa.cdst[2] = wkpb; pa.cn[2] = D * D;
  pa.csrc[3] = Wvp; pa.cdst[3] = wvpb; pa.cn[3] = D * D;
  pa.csrc[4] = Wo;  pa.cdst[4] = wob;  pa.cn[4] = D * D;
  pa.csrc[5] = W1;  pa.cdst[5] = w1b;  pa.cn[5] = HID * D;
  pa.csrc[6] = W2;  pa.cdst[6] = w2b;  pa.cn[6] = D * HID;
  int pre = 0;
  for (int e = 0; e < 7; ++e) { pa.cpre[e] = pre; pre += pa.cn[e] / 2048; }
  pa.cpre[7] = pre;  // = 7168
  pa.Wq = Wq; pa.Wk = Wk; pa.Wv = Wv; pa.wdst = wqTb;
  pa.Wqp = Wqp; pa.Wkp = Wkp; pa.Wvp = Wvp;
  pa.bq = bq; pa.bqp = bqp; pa.bk = bk; pa.bkp = bkp; pa.bv = bv; pa.bvp = bvp;
  pa.bout = bfused;
  pa.sp = sp; pa.pout = spsb;
  prep_k<<<dim3(7168 + 768 + 768 + 512), dim3(256), 0, stream>>>(pa);

  // 2. weight-combine GEMMs: W' = Wp @ Worig (z-batched)
  gemm_k<64, 1><<<dim3(16, 8, 3), dim3(256), 0, stream>>>(
      wqpb, wqTb, (const float*)nullptr, wfused, D, D, D, 0, 1.f,
      (ushort*)nullptr, (const ushort*)nullptr, (const float*)nullptr);
  // 3. fused QKV projection; V block written transposed directly to vT
  gemm_k<64, 0><<<dim3(32, 24), dim3(256), 0, stream>>>(
      xb, wfused, bfused, qkv, L, 3072, D, 0, 1.f,
      vT, (const ushort*)nullptr, (const float*)nullptr);

  // 4. attention (QBLK=128, KV-split=4, XCD-swizzled 1-D grid, gload_lds staging)
  attn_k<<<dim3(H * (L / 128) * 4), dim3(256), 0, stream>>>(qkv, vT, spsb, opart, lbuf);

  // 5. output projection with FUSED acomb A-staging (split-K4, bf16 partials) + LN1
  gemm_k<64, 3><<<dim3(32, 8, 4), dim3(256), 0, stream>>>(
      opart, wob, (const float*)nullptr, parts, L, D, D, 0, 1.f,
      (ushort*)nullptr, opart, lbuf);
  lnf_k<<<dim3(L), dim3(256), 0, stream>>>(x, parts, bo, g1, be1, 0, hb, hf);
  // 6. FFN1 (relu, BM=64, 1024-block grid)
  gemm_k<64, 0><<<dim3(32, 32), dim3(256), 0, stream>>>(
      hb, w1b, b1, ffn1, L, HID, D, 1, 1.f,
      (ushort*)nullptr, (const ushort*)nullptr, (const float*)nullptr);
  // 7. FFN2 (split-K4) + fused relu+combine into LN2 -> fp32 out
  gemm_k<64, 2><<<dim3(32, 8, 4), dim3(256), 0, stream>>>(
      ffn1, w2b, (const float*)nullptr, parts, L, D, HID, 0, 1.f,
      (ushort*)nullptr, (const ushort*)nullptr, (const float*)nullptr);
  lnf_k<<<dim3(L), dim3(256), 0, stream>>>(hf, parts, b2, g2, be2, 1, (ushort*)nullptr, out);
}

// Round 25
// 182.862 us; speedup vs baseline: 1.0059x; 1.0059x over previous
//
#include <hip/hip_runtime.h>

typedef __attribute__((ext_vector_type(4))) float f32x4;
typedef __attribute__((ext_vector_type(8))) short s16x8;

static __device__ __forceinline__ ushort f2b(float f) {
  union { float f; unsigned u; } v; v.f = f;
  unsigned u = v.u;
  unsigned r = (u + 0x7fffu + ((u >> 16) & 1u)) >> 16;
  return (ushort)r;
}
static __device__ __forceinline__ float b2f(ushort h) {
  union { unsigned u; float f; } v; v.u = ((unsigned)h) << 16;
  return v.f;
}
static __device__ __forceinline__ unsigned cvtpk(float a, float b) {
  unsigned r;
  asm("v_cvt_pk_bf16_f32 %0, %1, %2" : "=v"(r) : "v"(a), "v"(b));
  return r;
}
static __device__ __forceinline__ float exp2i(float x) {
  float r;
  asm("v_exp_f32 %0, %1" : "=v"(r) : "v"(x));
  return r;
}

static __device__ __forceinline__ void gload_lds16(const ushort* g, ushort* l) {
  __builtin_amdgcn_global_load_lds(
      (const __attribute__((address_space(1))) void*)g,
      (__attribute__((address_space(3))) void*)l, 16, 0, 0);
}

#define LOG2E 1.44269504f

// ---------------- fused preprocessing: cvt(7 regions, 2xILP) + wtr + bvec + spsm ----------------
struct PrepArgs {
  const float* csrc[7];
  ushort* cdst[7];
  int cn[7];
  int cpre[8];
  const float* Wq; const float* Wk; const float* Wv; ushort* wdst;
  const float* Wqp; const float* Wkp; const float* Wvp;
  const float* bq; const float* bqp; const float* bk; const float* bkp;
  const float* bv; const float* bvp; float* bout;
  const float* sp; ushort* pout;
};

__global__ __launch_bounds__(256) void prep_k(PrepArgs a) {
  __shared__ char shmem[16672];
  int b = blockIdx.x;
  int tid = threadIdx.x;

  if (b < 7168) {  // ---- cvt: 2048 elems/block, 2 float4 per thread ----
    int e = 0;
#pragma unroll
    for (int k = 1; k < 7; ++k) e += (b >= a.cpre[k]) ? 1 : 0;
    int base = (b - a.cpre[e]) * 2048 + tid * 4;
    if (base + 1024 + 4 <= a.cn[e] || base + 4 <= a.cn[e]) {
      float4 v4a = *(const float4*)(a.csrc[e] + base);
      float4 v4b = *(const float4*)(a.csrc[e] + base + 1024);
      ushort4 o4a, o4b;
      o4a.x = f2b(v4a.x); o4a.y = f2b(v4a.y); o4a.z = f2b(v4a.z); o4a.w = f2b(v4a.w);
      o4b.x = f2b(v4b.x); o4b.y = f2b(v4b.y); o4b.z = f2b(v4b.z); o4b.w = f2b(v4b.w);
      *(ushort4*)(a.cdst[e] + base) = o4a;
      *(ushort4*)(a.cdst[e] + base + 1024) = o4b;
    }
    return;
  }
  b -= 7168;
  if (b < 768) {    // ---- wtr ----
    float (*t)[65] = (float(*)[65])shmem;
    int z = b >> 8, rem = b & 255;
    const float* src = z == 0 ? a.Wq : (z == 1 ? a.Wk : a.Wv);
    float scale = z == 0 ? 0.125f * LOG2E : 1.f;
    int r0 = (rem >> 4) * 64, c0 = (rem & 15) * 64;
    int lr = tid >> 2, lc4 = (tid & 3) * 16;
#pragma unroll
    for (int j = 0; j < 4; ++j)
      *(float4*)&t[lr][lc4 + j * 4] = *(const float4*)(src + (size_t)(r0 + lr) * 1024 + c0 + lc4 + j * 4);
    __syncthreads();
    ushort tmp[16];
#pragma unroll
    for (int j = 0; j < 16; ++j) tmp[j] = f2b(t[lc4 + j][lr] * scale);
    ushort* d = a.wdst + (size_t)z * 1048576 + (size_t)(c0 + lr) * 1024 + r0 + lc4;
    *(uint4*)d = *(uint4*)tmp;
    *(uint4*)(d + 8) = *(uint4*)(tmp + 8);
    return;
  }
  b -= 768;
  if (b < 768) {    // ---- bvec ----
    int r = b * 4 + (tid >> 6);
    int lane = tid & 63;
    int z = r >> 10, rr = r & 1023;
    const float* Wp = z == 0 ? a.Wqp : (z == 1 ? a.Wkp : a.Wvp);
    const float* bi = z == 0 ? a.bq : (z == 1 ? a.bk : a.bv);
    const float* bp = z == 0 ? a.bqp : (z == 1 ? a.bkp : a.bvp);
    float s = 0.f;
#pragma unroll
    for (int t2 = 0; t2 < 4; ++t2) {
      float4 w = *(const float4*)(Wp + (size_t)rr * 1024 + lane * 16 + t2 * 4);
      float4 bb = *(const float4*)(bi + lane * 16 + t2 * 4);
      s += w.x * bb.x + w.y * bb.y + w.z * bb.z + w.w * bb.w;
    }
#pragma unroll
    for (int m = 1; m < 64; m <<= 1) s += __shfl_xor(s, m);
    if (lane == 0) a.bout[r] = (s + bp[rr]) * (z == 0 ? 0.125f * LOG2E : 1.f);
    return;
  }
  b -= 768;
  {                 // ---- spsm: 4 rows/block, bf16 LDS staging, coalesced writes ----
    const int Lc = 2048;
    ushort (*vals)[2048] = (ushort(*)[2048])shmem;
    float* invs = (float*)(shmem + 4 * 2048 * 2);
    int row0 = b * 4;
    int grp = tid >> 6;
    int lane = tid & 63;
    const float* r = a.sp + (size_t)(row0 + grp) * Lc;
    float v[32];
    float mx = -1e30f;
#pragma unroll
    for (int c = 0; c < 8; ++c) {
      float4 f = *(const float4*)(r + lane * 4 + c * 256);
      v[c * 4 + 0] = f.x; v[c * 4 + 1] = f.y; v[c * 4 + 2] = f.z; v[c * 4 + 3] = f.w;
      mx = fmaxf(mx, fmaxf(fmaxf(f.x, f.y), fmaxf(f.z, f.w)));
    }
#pragma unroll
    for (int m = 1; m < 64; m <<= 1) mx = fmaxf(mx, __shfl_xor(mx, m));
    float s = 0.f;
#pragma unroll
    for (int j = 0; j < 32; ++j) { v[j] = __expf(v[j] - mx); s += v[j]; }
#pragma unroll
    for (int m = 1; m < 64; m <<= 1) s += __shfl_xor(s, m);
    if (lane == 0) invs[grp] = 0.5f * LOG2E / s;
#pragma unroll
    for (int c = 0; c < 8; ++c) {
      ushort4 st;
      st.x = f2b(v[c * 4 + 0]); st.y = f2b(v[c * 4 + 1]);
      st.z = f2b(v[c * 4 + 2]); st.w = f2b(v[c * 4 + 3]);
      *(ushort4*)&vals[grp][lane * 4 + c * 256] = st;
    }
    __syncthreads();
    int mb = row0 >> 6, rr = row0 & 63;
    int wv = rr >> 4, rg = (rr & 15) >> 2;
    float iv0 = invs[0], iv1 = invs[1], iv2 = invs[2], iv3 = invs[3];
#pragma unroll
    for (int half = 0; half < 2; ++half) {
      int seg = tid + half * 256;
      int nb = seg >> 4, cl = seg & 15;
      ushort ov[16];
#pragma unroll
      for (int nt = 0; nt < 4; ++nt) {
        int col = nb * 64 + nt * 16 + cl;
        ov[0 * 4 + nt] = f2b(b2f(vals[0][col]) * iv0);
        ov[1 * 4 + nt] = f2b(b2f(vals[1][col]) * iv1);
        ov[2 * 4 + nt] = f2b(b2f(vals[2][col]) * iv2);
        ov[3 * 4 + nt] = f2b(b2f(vals[3][col]) * iv3);
      }
      ushort* dst = a.pout + ((size_t)(mb * 32 + nb)) * 4096 + wv * 1024 + rg * 256 + cl * 16;
      *(uint4*)dst = *(uint4*)&ov[0];
      *(uint4*)(dst + 8) = *(uint4*)&ov[8];
    }
  }
}

// ---------------- bf16 GEMM, dbuf 2-phase, T2 XOR-swizzled LDS ----------------
// vTout != nullptr (QKV gemm only): columns >= 2048 (V block) are written
// TRANSPOSED to vTout[(c-2048)][r] as one 8B ushort4 per thread.
template <int BM, int ZM>
__global__ __launch_bounds__(256, BM == 64 ? 3 : 2) void gemm_k(
    const ushort* __restrict__ A, const ushort* __restrict__ W,
    const float* __restrict__ bias, void* __restrict__ Cv,
    int M, int N, int K, int relu, float oscale,
    ushort* __restrict__ vTout) {
  constexpr int MT = BM / 32;
  __shared__ ushort As0[BM][64], Bs0[128][64];
  __shared__ ushort As1[BM][64], Bs1[128][64];
  const int z = (ZM != 0) ? blockIdx.z : 0;
  if (ZM == 1) { A += (size_t)z * M * K; W += (size_t)z * N * K; }
  int kb0 = 0, kb1 = K;
  if (ZM == 2) { int kh = K >> 2; kb0 = z * kh; kb1 = kb0 + kh; }
  const int tid = threadIdx.x;
  const int lane = tid & 63;
  const int wave = tid >> 6;
  const int wm = (wave >> 1) * (BM / 2);
  const int wn = (wave & 1) * 64;
  const int bm = blockIdx.x * BM;
  const int bn = blockIdx.y * 128;
  const int cl = lane & 15, rg = lane >> 4;
  const int lrow = lane >> 3;
  const int lcol = ((lane & 7) ^ lrow) * 8;  // swizzled global source column

  f32x4 acc[MT][4];
#pragma unroll
  for (int i = 0; i < MT; ++i)
#pragma unroll
    for (int j = 0; j < 4; ++j) acc[i][j] = (f32x4){0.f, 0.f, 0.f, 0.f};

  const ushort* gA = A + (size_t)(bm + wave * 8 + lrow) * K + lcol;
  const ushort* gB = W + (size_t)(bn + wave * 8 + lrow) * K + lcol;

  auto stage = [&](ushort* lA, ushort* lB, int k0) {
#pragma unroll
    for (int c = 0; c < MT; ++c)
      gload_lds16(gA + (size_t)(c * 32) * K + k0, lA + wave * 512 + c * 2048);
#pragma unroll
    for (int c = 0; c < 4; ++c)
      gload_lds16(gB + (size_t)(c * 32) * K + k0, lB + wave * 512 + c * 2048);
  };
  auto compute = [&](const ushort* As, const ushort* Bs) {
#pragma unroll
    for (int kk = 0; kk < 64; kk += 32) {
      const int slot = (kk >> 3) + rg;  // global k-slot 0..7
      s16x8 af[MT], bf[4];
#pragma unroll
      for (int mt = 0; mt < MT; ++mt) {
        int r = wm + mt * 16 + cl;
        af[mt] = *(const s16x8*)(As + r * 64 + ((slot ^ (r & 7)) << 3));
      }
#pragma unroll
      for (int nt = 0; nt < 4; ++nt) {
        int r = wn + nt * 16 + cl;
        bf[nt] = *(const s16x8*)(Bs + r * 64 + ((slot ^ (r & 7)) << 3));
      }
#pragma unroll
      for (int mt = 0; mt < MT; ++mt)
#pragma unroll
        for (int nt = 0; nt < 4; ++nt)
          acc[mt][nt] = __builtin_amdgcn_mfma_f32_16x16x32_bf16(af[mt], bf[nt], acc[mt][nt], 0, 0, 0);
    }
  };

  const int ktiles = (kb1 - kb0) >> 6;  // all our K sizes give an even count
  stage(&As0[0][0], &Bs0[0][0], kb0);
  __syncthreads();
  for (int tt = 0; tt < ktiles; tt += 2) {
    stage(&As1[0][0], &Bs1[0][0], kb0 + (tt + 1) * 64);
    compute(&As0[0][0], &Bs0[0][0]);
    __syncthreads();
    if (tt + 2 < ktiles) stage(&As0[0][0], &Bs0[0][0], kb0 + (tt + 2) * 64);
    compute(&As1[0][0], &Bs1[0][0]);
    __syncthreads();
  }

  ushort* Cu = (ushort*)Cv;
  if (ZM != 0) Cu += (size_t)z * M * N;
#pragma unroll
  for (int nt = 0; nt < 4; ++nt) {
    int c = bn + wn + nt * 16 + cl;
    float bv = (bias && ZM != 2) ? bias[c] : 0.f;
#pragma unroll
    for (int mt = 0; mt < MT; ++mt) {
      float v0 = (acc[mt][nt][0] + bv) * oscale;
      float v1 = (acc[mt][nt][1] + bv) * oscale;
      float v2 = (acc[mt][nt][2] + bv) * oscale;
      float v3 = (acc[mt][nt][3] + bv) * oscale;
      if (relu) {
        v0 = fmaxf(v0, 0.f); v1 = fmaxf(v1, 0.f);
        v2 = fmaxf(v2, 0.f); v3 = fmaxf(v3, 0.f);
      }
      unsigned p01 = cvtpk(v0, v1), p23 = cvtpk(v2, v3);
      int r0 = bm + wm + mt * 16 + rg * 4;
      if (ZM == 0 && vTout != nullptr && c >= 2048) {
        // V block: write transposed, 4 consecutive rows = one 8B store
        ushort4 ov;
        ov.x = (ushort)p01; ov.y = (ushort)(p01 >> 16);
        ov.z = (ushort)p23; ov.w = (ushort)(p23 >> 16);
        *(ushort4*)(vTout + (size_t)(c - 2048) * 2048 + r0) = ov;
      } else {
        size_t b = (size_t)r0 * N + c;
        Cu[b] = (ushort)p01;
        Cu[b + N] = (ushort)(p01 >> 16);
        Cu[b + 2 * N] = (ushort)p23;
        Cu[b + 3 * N] = (ushort)(p23 >> 16);
      }
    }
  }
}

// ---------------- flash attention: QBLK=128, exp2 softmax, KV-split=4 ----------------
__global__ __launch_bounds__(256, 4) void attn_k(
    const ushort* __restrict__ qkv, const ushort* __restrict__ vT,
    const ushort* __restrict__ biasP, ushort* __restrict__ opart,
    float* __restrict__ lbuf) {
  const int Lc = 2048;
  int bid = blockIdx.x;
  int xcd = bid & 7;
  int idx = bid >> 3;            // 0..127
  int h = idx & 15;
  int combo = xcd * 8 + (idx >> 4);  // 0..63
  int m0 = (combo & 15) * 128;
  int s = combo >> 4;
  int nb = s * 512, ne = nb + 512;
  int tid = threadIdx.x, lane = tid & 63, wave = tid >> 6;

  __shared__ ushort KsL[64 * 64];
  __shared__ ushort VsL[64 * 64];
  __shared__ ushort Ps[4][2][16][72];

  const int rg = lane >> 4, cl = lane & 15;
  const int kb = 8 * rg;
  const int pskey = (cl >> 2) << 3;  // Ps read-side XOR key (row = cl)
  const int lr = lane >> 3, lc = lane & 7;
  const int ssw = (lc ^ lr) * 8;     // swizzled global source slot

  s16x8 qfr[2][2];
#pragma unroll
  for (int mh = 0; mh < 2; ++mh) {
    const ushort* qp = qkv + (size_t)(m0 + mh * 64 + wave * 16 + cl) * 3072 + h * 64;
    qfr[mh][0] = *(const s16x8*)(qp + kb);
    qfr[mh][1] = *(const s16x8*)(qp + 32 + kb);
  }

  // per-thread-contiguous bias bases: [(mb*32+nb)][wave][lane][16]
  const ushort* bpB0 = biasP + ((size_t)(m0 >> 6) * 32) * 4096 + (size_t)wave * 1024 + lane * 16;
  const ushort* bpB1 = bpB0 + (size_t)32 * 4096;

  f32x4 oacc[2][4];
#pragma unroll
  for (int mh = 0; mh < 2; ++mh)
#pragma unroll
    for (int i = 0; i < 4; ++i) oacc[mh][i] = (f32x4){0.f, 0.f, 0.f, 0.f};
  float lacc[2][4] = {{0.f, 0.f, 0.f, 0.f}, {0.f, 0.f, 0.f, 0.f}};

  const ushort* gK = qkv + 1024 + h * 64 + ssw;
  const ushort* gV = vT + (size_t)h * 64 * 2048 + ssw;

  for (int n0 = nb; n0 < ne; n0 += 64) {
    __syncthreads();
#pragma unroll
    for (int pp = 0; pp < 2; ++pp) {
      int rbase = wave * 8 + pp * 32;
      int row = rbase + lr;
      gload_lds16(gK + (size_t)(n0 + row) * 3072, &KsL[rbase * 64]);
      gload_lds16(gV + (size_t)row * 2048 + n0, &VsL[rbase * 64]);
    }
    __syncthreads();

#pragma unroll
    for (int mh = 0; mh < 2; ++mh) {
      const ushort* bp = (mh ? bpB1 : bpB0) + (size_t)(n0 >> 6) * 4096;
      uint4 bv0 = *(const uint4*)bp;
      uint4 bv1 = *(const uint4*)(bp + 8);
      ushort bvals[16];
      *(uint4*)&bvals[0] = bv0;
      *(uint4*)&bvals[8] = bv1;
      f32x4 sacc[4];
#pragma unroll
      for (int i = 0; i < 4; ++i)
#pragma unroll
        for (int nt = 0; nt < 4; ++nt)
          sacc[nt][i] = b2f(bvals[i * 4 + nt]);

      __builtin_amdgcn_s_setprio(1);
#pragma unroll
      for (int kk2 = 0; kk2 < 2; ++kk2) {
#pragma unroll
        for (int nt = 0; nt < 4; ++nt) {
          int r = nt * 16 + cl;
          s16x8 b = *(const s16x8*)&KsL[r * 64 + (((kk2 * 4 + rg) ^ (cl & 7)) << 3)];
          sacc[nt] = __builtin_amdgcn_mfma_f32_16x16x32_bf16(qfr[mh][kk2], b, sacc[nt], 0, 0, 0);
        }
      }
      __builtin_amdgcn_s_setprio(0);

#pragma unroll
      for (int i = 0; i < 4; ++i) {
#pragma unroll
        for (int nt = 0; nt < 4; ++nt) {
          float pv = exp2i(sacc[nt][i]);
          sacc[nt][i] = pv;
          lacc[mh][i] += pv;
        }
      }
      const int wkey = rg << 3;
#pragma unroll
      for (int nt = 0; nt < 4; ++nt) {
        int colb = (nt * 16 + cl) ^ wkey;
        unsigned p01 = cvtpk(sacc[nt][0], sacc[nt][1]);
        unsigned p23 = cvtpk(sacc[nt][2], sacc[nt][3]);
        Ps[wave][mh][rg * 4 + 0][colb] = (ushort)p01;
        Ps[wave][mh][rg * 4 + 1][colb] = (ushort)(p01 >> 16);
        Ps[wave][mh][rg * 4 + 2][colb] = (ushort)p23;
        Ps[wave][mh][rg * 4 + 3][colb] = (ushort)(p23 >> 16);
      }
    }

    __builtin_amdgcn_s_setprio(1);
#pragma unroll
    for (int mh = 0; mh < 2; ++mh) {
#pragma unroll
      for (int kk = 0; kk < 64; kk += 32) {
        s16x8 a = *(const s16x8*)&Ps[wave][mh][cl][(kk + kb) ^ pskey];
#pragma unroll
        for (int nt = 0; nt < 4; ++nt) {
          int r = nt * 16 + cl;
          s16x8 b = *(const s16x8*)&VsL[r * 64 + ((((kk >> 3) + rg) ^ (cl & 7)) << 3)];
          oacc[mh][nt] = __builtin_amdgcn_mfma_f32_16x16x32_bf16(a, b, oacc[mh][nt], 0, 0, 0);
        }
      }
    }
    __builtin_amdgcn_s_setprio(0);
  }

#pragma unroll
  for (int mh = 0; mh < 2; ++mh) {
#pragma unroll
    for (int nt = 0; nt < 4; ++nt) {
      unsigned p01 = cvtpk(oacc[mh][nt][0], oacc[mh][nt][1]);
      unsigned p23 = cvtpk(oacc[mh][nt][2], oacc[mh][nt][3]);
      size_t b = ((size_t)s * Lc + (m0 + mh * 64 + wave * 16 + rg * 4)) * 1024 + h * 64 + nt * 16 + cl;
      opart[b] = (ushort)p01;
      opart[b + 1024] = (ushort)(p01 >> 16);
      opart[b + 2048] = (ushort)p23;
      opart[b + 3072] = (ushort)(p23 >> 16);
    }
#pragma unroll
    for (int i = 0; i < 4; ++i) {
      float l = lacc[mh][i];
#pragma unroll
      for (int m = 1; m < 16; m <<= 1) l += __shfl_xor(l, m);
      if (cl == 0) {
        int r = m0 + mh * 64 + wave * 16 + rg * 4 + i;
        lbuf[(size_t)(s * 16 + h) * Lc + r] = l;
      }
    }
  }
}

// ---------------- combine 4 KV-splits: O = sum(O_s)/sum(l_s) ----------------
__global__ __launch_bounds__(256) void acomb_k(const ushort* __restrict__ op,
                                               const float* __restrict__ lbuf,
                                               ushort* __restrict__ ob) {
  const int Lc = 2048;
  int qrow = blockIdx.x;
  int tid = threadIdx.x;
  int c = tid * 4;
  int h = c >> 6;
  float lsum = 0.f;
#pragma unroll
  for (int s = 0; s < 4; ++s) lsum += lbuf[(size_t)(s * 16 + h) * Lc + qrow];
  float inv = 1.f / lsum;
  float acc0 = 0.f, acc1 = 0.f, acc2 = 0.f, acc3 = 0.f;
#pragma unroll
  for (int s = 0; s < 4; ++s) {
    ushort4 a = *(const ushort4*)(op + ((size_t)s * Lc + qrow) * 1024 + c);
    acc0 += b2f(a.x); acc1 += b2f(a.y); acc2 += b2f(a.z); acc3 += b2f(a.w);
  }
  ushort4 o;
  o.x = f2b(acc0 * inv); o.y = f2b(acc1 * inv);
  o.z = f2b(acc2 * inv); o.w = f2b(acc3 * inv);
  *(ushort4*)(ob + (size_t)qrow * 1024 + c) = o;
}

// ---------------- fused 4-way split-K combine (bf16 partials) + residual + LayerNorm ----------------
__global__ __launch_bounds__(256) void lnf_k(const float* __restrict__ basef,
                                             const ushort* __restrict__ p,
                                             const float* __restrict__ bvec,
                                             const float* __restrict__ g,
                                             const float* __restrict__ be,
                                             int relu,
                                             ushort* __restrict__ outb,
                                             float* __restrict__ outf) {
  const int Dc = 1024;
  const size_t MN = (size_t)2048 * 1024;
  int row = blockIdx.x;
  int tid = threadIdx.x;
  int c = tid * 4;
  float4 bx = *(const float4*)(basef + (size_t)row * Dc + c);
  float4 bb = *(const float4*)(bvec + c);
  float v0 = bb.x, v1 = bb.y, v2 = bb.z, v3 = bb.w;
#pragma unroll
  for (int s = 0; s < 4; ++s) {
    ushort4 a = *(const ushort4*)(p + s * MN + (size_t)row * Dc + c);
    v0 += b2f(a.x); v1 += b2f(a.y); v2 += b2f(a.z); v3 += b2f(a.w);
  }
  if (relu) {
    v0 = fmaxf(v0, 0.f); v1 = fmaxf(v1, 0.f);
    v2 = fmaxf(v2, 0.f); v3 = fmaxf(v3, 0.f);
  }
  v0 += bx.x; v1 += bx.y; v2 += bx.z; v3 += bx.w;
  float s = v0 + v1 + v2 + v3;
  __shared__ float red[4];
#pragma unroll
  for (int m = 1; m < 64; m <<= 1) s += __shfl_xor(s, m);
  if ((tid & 63) == 0) red[tid >> 6] = s;
  __syncthreads();
  s = red[0] + red[1] + red[2] + red[3];
  float mu = s * (1.f / Dc);
  float d0 = v0 - mu, d1 = v1 - mu, d2 = v2 - mu, d3 = v3 - mu;
  float ss = d0 * d0 + d1 * d1 + d2 * d2 + d3 * d3;
  __syncthreads();
#pragma unroll
  for (int m = 1; m < 64; m <<= 1) ss += __shfl_xor(ss, m);
  if ((tid & 63) == 0) red[tid >> 6] = ss;
  __syncthreads();
  ss = red[0] + red[1] + red[2] + red[3];
  float rs = rsqrtf(ss * (1.f / Dc) + 1e-5f);
  float4 gv = *(const float4*)(g + c);
  float4 bev = *(const float4*)(be + c);
  float y0 = d0 * rs * gv.x + bev.x;
  float y1 = d1 * rs * gv.y + bev.y;
  float y2 = d2 * rs * gv.z + bev.z;
  float y3 = d3 * rs * gv.w + bev.w;
  size_t o = (size_t)row * Dc + c;
  if (outb) {
    ushort4 ob4; ob4.x = f2b(y0); ob4.y = f2b(y1); ob4.z = f2b(y2); ob4.w = f2b(y3);
    *(ushort4*)(outb + o) = ob4;
  }
  if (outf) {
    float4 of4; of4.x = y0; of4.y = y1; of4.z = y2; of4.w = y3;
    *(float4*)(outf + o) = of4;
  }
}

extern "C" void kernel_launch(void* const* d_in, const int* in_sizes, int n_in,
                              void* d_out, int out_size, void* d_ws, size_t ws_size,
                              hipStream_t stream) {
  const int L = 2048, D = 1024, H = 16, HID = 4096;
  const float* x   = (const float*)d_in[0];
  const float* sp  = (const float*)d_in[1];
  const float* Wq  = (const float*)d_in[2];  const float* bq  = (const float*)d_in[3];
  const float* Wk  = (const float*)d_in[4];  const float* bk  = (const float*)d_in[5];
  const float* Wv  = (const float*)d_in[6];  const float* bv  = (const float*)d_in[7];
  const float* Wqp = (const float*)d_in[8];  const float* bqp = (const float*)d_in[9];
  const float* Wkp = (const float*)d_in[10]; const float* bkp = (const float*)d_in[11];
  const float* Wvp = (const float*)d_in[12]; const float* bvp = (const float*)d_in[13];
  const float* Wo  = (const float*)d_in[14]; const float* bo  = (const float*)d_in[15];
  const float* W1  = (const float*)d_in[16]; const float* b1  = (const float*)d_in[17];
  const float* W2  = (const float*)d_in[18]; const float* b2  = (const float*)d_in[19];
  const float* g1  = (const float*)d_in[20]; const float* be1 = (const float*)d_in[21];
  const float* g2  = (const float*)d_in[22]; const float* be2 = (const float*)d_in[23];
  float* out = (float*)d_out;

  size_t off = 0;
  char* base = (char*)d_ws;
  auto alloc = [&](size_t b) {
    char* p = base + off;
    off += (b + 255) & ~(size_t)255;
    return p;
  };
  ushort* xb    = (ushort*)alloc((size_t)L * D * 2);
  ushort* wqpb  = (ushort*)alloc((size_t)D * D * 2);   // three contiguous (z-batch)
  ushort* wkpb  = (ushort*)alloc((size_t)D * D * 2);
  ushort* wvpb  = (ushort*)alloc((size_t)D * D * 2);
  ushort* wqTb  = (ushort*)alloc((size_t)3 * D * D * 2);
  ushort* wfused= (ushort*)alloc((size_t)3 * D * D * 2);
  ushort* qkv   = (ushort*)alloc((size_t)L * 3072 * 2);
  float*  bfused= (float*)alloc((size_t)3072 * 4);
  ushort* wob   = (ushort*)alloc((size_t)D * D * 2);
  ushort* w1b   = (ushort*)alloc((size_t)HID * D * 2);
  ushort* w2b   = (ushort*)alloc((size_t)D * HID * 2);
  ushort* spsb  = (ushort*)alloc((size_t)L * L * 2);
  ushort* opart = (ushort*)alloc((size_t)4 * L * 1024 * 2);  // attn partials; reused as split-K parts
  ushort* vT    = (ushort*)alloc((size_t)H * 64 * L * 2);
  float*  lbuf  = (float*)alloc((size_t)4 * H * L * 4);
  ushort* ob    = (ushort*)alloc((size_t)L * 1024 * 2);
  ushort* hb    = (ushort*)alloc((size_t)L * D * 2);
  float*  hf    = (float*)alloc((size_t)L * D * 4);

  ushort* ffn1  = wqTb;    // R1 reuse (16.8MB < 25.2MB region)
  ushort* parts = opart;   // 4x bf16 partials (16.8MB), opart dead after acomb

  // 1. fused preprocessing: cvt(7, 2xILP) + wtr + bvec + spsm in ONE launch
  PrepArgs pa;
  pa.csrc[0] = x;   pa.cdst[0] = xb;   pa.cn[0] = L * D;
  pa.csrc[1] = Wqp; pa.cdst[1] = wqpb; pa.cn[1] = D * D;
  pa.csrc[2] = Wkp; pa.cdst[2] = wkpb; pa.cn[2] = D * D;
  pa.csrc[3] = Wvp; pa.cdst[3] = wvpb; pa.cn[3] = D * D;
  pa.csrc[4] = Wo;  pa.cdst[4] = wob;  pa.cn[4] = D * D;
  pa.csrc[5] = W1;  pa.cdst[5] = w1b;  pa.cn[5] = HID * D;
  pa.csrc[6] = W2;  pa.cdst[6] = w2b;  pa.cn[6] = D * HID;
  int pre = 0;
  for (int e = 0; e < 7; ++e) { pa.cpre[e] = pre; pre += pa.cn[e] / 2048; }
  pa.cpre[7] = pre;  // = 7168
  pa.Wq = Wq; pa.Wk = Wk; pa.Wv = Wv; pa.wdst = wqTb;
  pa.Wqp = Wqp; pa.Wkp = Wkp; pa.Wvp = Wvp;
  pa.bq = bq; pa.bqp = bqp; pa.bk = bk; pa.bkp = bkp; pa.bv = bv; pa.bvp = bvp;
  pa.bout = bfused;
  pa.sp = sp; pa.pout = spsb;
  prep_k<<<dim3(7168 + 768 + 768 + 512), dim3(256), 0, stream>>>(pa);

  // 2. weight-combine GEMMs: W' = Wp @ Worig (z-batched)
  gemm_k<64, 1><<<dim3(16, 8, 3), dim3(256), 0, stream>>>(
      wqpb, wqTb, (const float*)nullptr, wfused, D, D, D, 0, 1.f, (ushort*)nullptr);
  // 3. fused QKV projection; V block written transposed directly to vT
  gemm_k<64, 0><<<dim3(32, 24), dim3(256), 0, stream>>>(
      xb, wfused, bfused, qkv, L, 3072, D, 0, 1.f, vT);

  // 4. attention (QBLK=128, KV-split=4, XCD-swizzled 1-D grid, gload_lds staging)
  attn_k<<<dim3(H * (L / 128) * 4), dim3(256), 0, stream>>>(qkv, vT, spsb, opart, lbuf);
  // 5. combine splits
  acomb_k<<<dim3(L), dim3(256), 0, stream>>>(opart, lbuf, ob);

  // 6. output projection (split-K4, bf16 partials) + fused combine into LN1
  gemm_k<64, 2><<<dim3(32, 8, 4), dim3(256), 0, stream>>>(
      ob, wob, (const float*)nullptr, parts, L, D, D, 0, 1.f, (ushort*)nullptr);
  lnf_k<<<dim3(L), dim3(256), 0, stream>>>(x, parts, bo, g1, be1, 0, hb, hf);
  // 7. FFN1 (relu, BM=64, 1024-block grid)
  gemm_k<64, 0><<<dim3(32, 32), dim3(256), 0, stream>>>(
      hb, w1b, b1, ffn1, L, HID, D, 1, 1.f, (ushort*)nullptr);
  // 8. FFN2 (split-K4) + fused relu+combine into LN2 -> fp32 out
  gemm_k<64, 2><<<dim3(32, 8, 4), dim3(256), 0, stream>>>(
      ffn1, w2b, (const float*)nullptr, parts, L, D, HID, 0, 1.f, (ushort*)nullptr);
  lnf_k<<<dim3(L), dim3(256), 0, stream>>>(hf, parts, b2, g2, be2, 1, (ushort*)nullptr, out);
}